// Round 5
// baseline (100.093 us; speedup 1.0000x reference)
//
#include <hip/hip_runtime.h>
#include <math.h>

// B=1024, D=128, H=128
#define Bn 1024
#define Dn 128
#define Hn 128

// ---------------- K1: all-pairs partial column sums ----------------
// grid (64 i-tiles x 4 j-slices) x 1024 threads = 256 blocks (1/CU).
// Thread (q = t>>6 in [0,16) -> 16 j's, c = t&63 -> cols 2c,2c+1) holds
// xi/acc for ALL 16 rows of its i-tile in registers; each xj float2 load is
// reused 32x (16 rows x 2 cols) from registers.
// Traffic: each j-row read once per block -> total 256 blocks x 128 KB
// = 33.5 MB (4x less than the R=4 design). VALU identical (512 elem/thread).
__global__ __launch_bounds__(1024) void k1_pairs(
    const float* __restrict__ x, float* __restrict__ ws) {
  const int t = threadIdx.x;
  const int c = t & 63;                         // col pair: cols 2c, 2c+1
  const int q = t >> 6;                         // j-subgroup in [0,16)
  const int i0 = blockIdx.x << 4;               // 16 i-rows
  const int j0 = (blockIdx.y << 8) + (q << 4);  // this thread's 16 j's

  __shared__ float2 red[16][16][64];  // 128 KB: [q][row][colpair]

  float2 xi[16];
#pragma unroll
  for (int r = 0; r < 16; ++r)
    xi[r] = *(const float2*)(x + (size_t)(i0 + r) * Dn + 2 * c);

  float2 acc[16];
#pragma unroll
  for (int r = 0; r < 16; ++r) acc[r] = make_float2(0.f, 0.f);

  const float2* xq = (const float2*)x + (size_t)j0 * (Dn / 2) + c;
#pragma unroll 1
  for (int jj = 0; jj < 16; jj += 8) {
    float2 xj[8];
#pragma unroll
    for (int u = 0; u < 8; ++u) xj[u] = xq[(size_t)(jj + u) * (Dn / 2)];
#pragma unroll
    for (int u = 0; u < 8; ++u) {
#pragma unroll
      for (int r = 0; r < 16; ++r) {
        acc[r].x += fabsf(xi[r].x - xj[u].x);
        acc[r].y += fabsf(xi[r].y - xj[u].y);
      }
    }
  }
#pragma unroll
  for (int r = 0; r < 16; ++r) red[q][r][c] = acc[r];
  __syncthreads();

  // reduce 16 q-groups -> this block's partial [16][128] -> ws
  // 1024 outputs (float2) = exactly one per thread.
  float* wsp = ws + ((size_t)(blockIdx.x << 2) + blockIdx.y) * (16 * Dn);
  {
    const int r = t >> 6, cc = t & 63;
    float2 v = make_float2(0.f, 0.f);
#pragma unroll
    for (int qq = 0; qq < 16; ++qq) {
      v.x += red[qq][r][cc].x;
      v.y += red[qq][r][cc].y;
    }
    *(float2*)(wsp + r * Dn + 2 * cc) = v;
  }
}

// ---------------- K2: reduce j-slice partials + epilogue ----------------
// 256 blocks x 256 threads; block b owns rows 4b..4b+3.
__global__ __launch_bounds__(256) void k2_epilogue(
    const float* __restrict__ x, const float* __restrict__ ws,
    const float* __restrict__ Wd, const float* __restrict__ bd,
    const float* __restrict__ Wt, const float* __restrict__ bt,
    const float* __restrict__ Wa, const float* __restrict__ ba,
    const float* __restrict__ Wr, const float* __restrict__ br,
    const float* __restrict__ gamma, const float* __restrict__ beta,
    float* __restrict__ out) {
  const int t = threadIdx.x;
  const int b = blockIdx.x;
  const int i0 = b << 2;

  __shared__ float xs[4][Dn];
  __shared__ float dms[4][Dn];
  __shared__ float ms[4][Hn];
  __shared__ float ys[4][Hn];
  __shared__ float wt_s[Dn];
  __shared__ float tau_s[4];  // 1/tau

  // partials for i-tile (b>>2) live at ws + (itile*4 + js)*16*Dn;
  // our 4 rows are local rows (b&3)*4 .. +3 within each partial.
  const float* wsp = ws + (size_t)(b >> 2) * 4 * (16 * Dn) + (size_t)(b & 3) * 4 * Dn;
#pragma unroll
  for (int s = t; s < 512; s += 256) {
    const int r = s >> 7, d = s & 127;
    float v = 0.f;
#pragma unroll
    for (int js = 0; js < 4; ++js) v += wsp[js * 16 * Dn + r * Dn + d];
    dms[r][d] = v * (1.0f / 1024.0f);
    xs[r][d] = x[(size_t)b * 512 + s];
  }
  if (t < 128) wt_s[t] = Wt[t];
  __syncthreads();

  // tau (one wave per row)
  {
    const int r = t >> 6, p = t & 63;
    float partial = xs[r][p] * wt_s[p] + xs[r][p + 64] * wt_s[p + 64];
#pragma unroll
    for (int off = 32; off; off >>= 1) partial += __shfl_xor(partial, off, 64);
    if (p == 0) {
      const float z = partial + bt[0];
      const float sp = fmaxf(z, 0.f) + log1pf(expf(-fabsf(z)));  // softplus
      tau_s[r] = 1.0f / (fmaxf(sp, 0.01f) + 1.0f);
    }
  }
  __syncthreads();

  // m = (Wd . dm + bd) / tau
  const int h = t & 127;
  const int g4 = t >> 7;
  const int r0 = 2 * g4, r1 = 2 * g4 + 1;
  {
    float m0 = bd[h], m1 = m0;
    const float4* w = (const float4*)(Wd + (size_t)h * Dn);
#pragma unroll 4
    for (int k4 = 0; k4 < Dn / 4; ++k4) {
      const float4 wv = w[k4];
      const int k = k4 * 4;
      m0 += wv.x * dms[r0][k] + wv.y * dms[r0][k + 1] + wv.z * dms[r0][k + 2] + wv.w * dms[r0][k + 3];
      m1 += wv.x * dms[r1][k] + wv.y * dms[r1][k + 1] + wv.z * dms[r1][k + 2] + wv.w * dms[r1][k + 3];
    }
    ms[r0][h] = m0 * tau_s[r0];
    ms[r1][h] = m1 * tau_s[r1];
  }
  __syncthreads();

  // y = relu(Wa . m + ba) + Wr . x + br
  {
    float q0 = ba[h], q1 = q0, c0 = br[h], c1 = c0;
    const float4* wa = (const float4*)(Wa + (size_t)h * Dn);
    const float4* wr = (const float4*)(Wr + (size_t)h * Dn);
#pragma unroll 4
    for (int k4 = 0; k4 < Dn / 4; ++k4) {
      const float4 av = wa[k4];
      const float4 rv = wr[k4];
      const int k = k4 * 4;
      q0 += av.x * ms[r0][k] + av.y * ms[r0][k + 1] + av.z * ms[r0][k + 2] + av.w * ms[r0][k + 3];
      q1 += av.x * ms[r1][k] + av.y * ms[r1][k + 1] + av.z * ms[r1][k + 2] + av.w * ms[r1][k + 3];
      c0 += rv.x * xs[r0][k] + rv.y * xs[r0][k + 1] + rv.z * xs[r0][k + 2] + rv.w * xs[r0][k + 3];
      c1 += rv.x * xs[r1][k] + rv.y * xs[r1][k + 1] + rv.z * xs[r1][k + 2] + rv.w * xs[r1][k + 3];
    }
    ys[r0][h] = fmaxf(q0, 0.f) + c0;
    ys[r1][h] = fmaxf(q1, 0.f) + c1;
  }
  __syncthreads();

  // LayerNorm (one wave per row)
  {
    const int r = t >> 6, p = t & 63;
    const float v0 = ys[r][p], v1 = ys[r][p + 64];
    float s = v0 + v1;
    float qq = v0 * v0 + v1 * v1;
#pragma unroll
    for (int off = 32; off; off >>= 1) {
      s += __shfl_xor(s, off, 64);
      qq += __shfl_xor(qq, off, 64);
    }
    const float mu = s * (1.0f / 128.0f);
    const float var = qq * (1.0f / 128.0f) - mu * mu;
    const float rs = rsqrtf(var + 1e-5f);
    float* o = out + (size_t)(i0 + r) * Hn;
    o[p]      = (v0 - mu) * rs * gamma[p]      + beta[p];
    o[p + 64] = (v1 - mu) * rs * gamma[p + 64] + beta[p + 64];
  }
}

extern "C" void kernel_launch(void* const* d_in, const int* in_sizes, int n_in,
                              void* d_out, int out_size, void* d_ws, size_t ws_size,
                              hipStream_t stream) {
  const float* x     = (const float*)d_in[0];
  const float* Wd    = (const float*)d_in[1];
  const float* bd    = (const float*)d_in[2];
  const float* Wt    = (const float*)d_in[3];
  const float* bt    = (const float*)d_in[4];
  const float* Wa    = (const float*)d_in[5];
  const float* ba    = (const float*)d_in[6];
  const float* Wr    = (const float*)d_in[7];
  const float* br    = (const float*)d_in[8];
  const float* gamma = (const float*)d_in[9];
  const float* beta  = (const float*)d_in[10];
  float* out = (float*)d_out;
  float* ws = (float*)d_ws;  // 64 itiles * 4 jslices * 16*128 floats = 2 MB

  dim3 g1(Bn / 16, 4);
  k1_pairs<<<g1, 1024, 0, stream>>>(x, ws);
  k2_epilogue<<<Bn / 4, 256, 0, stream>>>(x, ws, Wd, bd, Wt, bt, Wa, ba,
                                          Wr, br, gamma, beta, out);
  (void)in_sizes; (void)n_in; (void)out_size; (void)ws_size;
}